// Round 14
// baseline (84.277 us; speedup 1.0000x reference)
//
#include <hip/hip_runtime.h>

// Problem constants (match reference)
constexpr int B    = 64;
constexpr int E    = 512;
constexpr int P    = 31;    // patch size
constexpr int S    = 200;   // canvas size
constexpr int HALF = 15;

// Tiling: 32x32 canvas tiles
constexpr int TS     = 32;
constexpr int NTD    = (S + TS - 1) / TS;    // 7 tiles per dim
constexpr int NTILES = NTD * NTD;            // 49 tiles per batch
constexpr int NBINS  = B * NTILES;           // 3136
constexpr int CAP    = 128;                  // bin capacity (mean ~39, tail ~75)

constexpr int THREADS = 512;                 // one block per tile; 2 px per thread

__global__ __launch_bounds__(512)
void imgs4dto3d_bin_kernel(const int* __restrict__ xyz,
                           int*       __restrict__ counts,
                           unsigned*  __restrict__ entries)
{
    const int b = blockIdx.x;
    const int e = threadIdx.x;
    const int x = xyz[(size_t)(b * E + e) * 3 + 0];
    const int y = xyz[(size_t)(b * E + e) * 3 + 1];
    const unsigned pk = (unsigned)e | ((unsigned)x << 9) | ((unsigned)y << 17);

    const int tr_lo = (x - HALF) >> 5, tr_hi = (x + HALF) >> 5;   // at most 2 per dim
    const int tc_lo = (y - HALF) >> 5, tc_hi = (y + HALF) >> 5;

    for (int tr = tr_lo; tr <= tr_hi; ++tr) {
        for (int tc = tc_lo; tc <= tc_hi; ++tc) {
            const int bin = b * NTILES + tr * NTD + tc;
            const int pos = atomicAdd(&counts[bin], 1);
            if (pos < CAP) entries[(size_t)bin * CAP + pos] = pk;
        }
    }
}

__global__ __launch_bounds__(THREADS, 4)   // 4 blocks/CU = 32 waves/CU capacity
void imgs4dto3d_gather_kernel(const float*    __restrict__ img,
                              const int*      __restrict__ counts,
                              const unsigned* __restrict__ entries,
                              float*          __restrict__ out)
{
    const int b   = blockIdx.y;
    const int t   = blockIdx.x;             // tile index, 0..NTILES-1
    const int tid = threadIdx.x;

    const int tr = t / NTD;
    const int tc = t % NTD;
    const int r0 = tr * TS;
    const int c0 = tc * TS;

    // thread owns 2 rows of one column: col = tid&31 (coalesced), rowg = tid>>5 (0..15)
    const int col  = tid & 31;
    const int rowg = tid >> 5;
    const int c    = c0 + col;

    const int rr = r0 + rowg * 2 + HALF;    // pr0 = rr - x  (verified R6/R12/R13 math)
    const int cc = c + HALF;                // pc  = cc - y

    const int bin = b * NTILES + t;
    const int n   = min(counts[bin], CAP);
    const uint4* lst = reinterpret_cast<const uint4*>(entries + (size_t)bin * CAP);

    float a0 = 0.f, a1 = 0.f;
    const float* imgb = img + (size_t)b * E * (P * P);

    const int niter = (n + 3) >> 2;
    uint4 cur = (niter > 0) ? lst[0] : make_uint4(0u, 0u, 0u, 0u);
    for (int i = 0; i < niter; ++i) {
        const uint4 nxt = (i + 1 < niter) ? lst[i + 1] : cur;   // prefetch next 4 entries
        const unsigned pks[4] = {cur.x, cur.y, cur.z, cur.w};
        #pragma unroll
        for (int u = 0; u < 4; ++u) {
            const bool inb = (4 * i + u) < n;            // wave-uniform
            const unsigned pk = pks[u];
            const int e = (int)(pk & 511u);
            const int x = (int)((pk >> 9) & 255u);
            const int y = (int)(pk >> 17);

            const int pc  = cc - y;                      // patch col (fixed per lane)
            const int pr0 = rr - x;                      // patch row for q=0
            const bool colok = inb && ((unsigned)pc <= 30u);
            const size_t base = (size_t)e * (P * P);
            const bool k0 = colok && ((unsigned)(pr0 + 0) <= 30u);
            const bool k1 = colok && ((unsigned)(pr0 + 1) <= 30u);
            a0 += k0 ? imgb[base + (pr0 + 0) * P + pc] : 0.f;
            a1 += k1 ? imgb[base + (pr0 + 1) * P + pc] : 0.f;
        }
        cur = nxt;
    }

    // store: 32 consecutive lanes per row segment -> full 128B line writes
    if (c < S) {
        const int rb = r0 + rowg * 2;
        if (rb + 0 < S) out[(size_t)b * (S * S) + (rb + 0) * S + c] = a0;
        if (rb + 1 < S) out[(size_t)b * (S * S) + (rb + 1) * S + c] = a1;
    }
}

extern "C" void kernel_launch(void* const* d_in, const int* in_sizes, int n_in,
                              void* d_out, int out_size, void* d_ws, size_t ws_size,
                              hipStream_t stream)
{
    const float* img = (const float*)d_in[0];   // [B, E, P, P] fp32
    const int*   xyz = (const int*)d_in[1];     // [B, E, 3] int32
    float*       out = (float*)d_out;           // [B, 1, S, S] fp32

    int*      counts  = (int*)d_ws;
    unsigned* entries = (unsigned*)d_ws + NBINS;

    hipMemsetAsync(counts, 0, (size_t)NBINS * sizeof(int), stream);

    imgs4dto3d_bin_kernel<<<B, E, 0, stream>>>(xyz, counts, entries);

    dim3 grid(NTILES, B);                        // one block per (tile, batch)
    imgs4dto3d_gather_kernel<<<grid, THREADS, 0, stream>>>(img, counts, entries, out);
}

// Round 15
// 57.971 us; speedup vs baseline: 1.4538x; 1.4538x over previous
//
#include <hip/hip_runtime.h>

// Problem constants (match reference)
constexpr int B    = 64;
constexpr int E    = 512;
constexpr int P    = 31;    // patch size
constexpr int S    = 200;   // canvas size
constexpr int HALF = 15;

// Tiling: 16x16 canvas tiles (best test-efficiency: (16+30)^2 tests/emitter)
constexpr int TS     = 16;
constexpr int NTD    = (S + TS - 1) / TS;    // 13 tiles per dim
constexpr int NTILES = NTD * NTD;            // 169 tiles per batch
constexpr int NBINS  = B * NTILES;           // 10816
constexpr int CAP    = 128;                  // bin capacity (mean ~25, tail ~60)

// Gather launch: one BLOCK per tile; its 4 waves split the bin (R12-verified)
constexpr int THREADS = 256;
constexpr int NW      = THREADS / 64;        // 4 waves
constexpr int NXCD    = 8;

__global__ __launch_bounds__(256)
void imgs4dto3d_bin_kernel(const int* __restrict__ xyz,
                           int*       __restrict__ counts,
                           unsigned*  __restrict__ entries)
{
    const int b = blockIdx.x >> 1;
    const int e = ((blockIdx.x & 1) << 8) | threadIdx.x;
    const int x = xyz[(size_t)(b * E + e) * 3 + 0];
    const int y = xyz[(size_t)(b * E + e) * 3 + 1];
    const unsigned pk = (unsigned)e | ((unsigned)x << 9) | ((unsigned)y << 17);

    const int tr_lo = (x - HALF) >> 4, tr_hi = (x + HALF) >> 4;
    const int tc_lo = (y - HALF) >> 4, tc_hi = (y + HALF) >> 4;

    for (int tr = tr_lo; tr <= tr_hi; ++tr) {
        for (int tc = tc_lo; tc <= tc_hi; ++tc) {
            const int bin = b * NTILES + tr * NTD + tc;
            const int pos = atomicAdd(&counts[bin], 1);
            if (pos < CAP) entries[(size_t)bin * CAP + pos] = pk;
        }
    }
}

__global__ __launch_bounds__(THREADS, 8)
void imgs4dto3d_gather_kernel(const float*    __restrict__ img,
                              const int*      __restrict__ counts,
                              const unsigned* __restrict__ entries,
                              float*          __restrict__ out)
{
    // XCD-locality swizzle: all 169 tiles of a batch land on one XCD, so the
    // 2 MB batch slab stays resident in that XCD's 4 MB L2 across its tiles.
    // Bijective: gridDim.x = 10816 = 8 * 1352.
    const int wgid = blockIdx.x;
    const int xcd  = wgid & (NXCD - 1);
    const int seq  = wgid >> 3;
    const int b    = ((seq / NTILES) << 3) | xcd;
    const int t    = seq % NTILES;

    const int tid  = threadIdx.x;
    const int wid  = tid >> 6;
    const int lane = tid & 63;

    const int tr = t / NTD;
    const int tc = t % NTD;
    const int r0 = tr * TS;
    const int c0 = tc * TS;

    // lane map (R6/R12-verified): col = lane&15, rowg = lane>>4; 4 rows per lane
    const int col  = lane & 15;
    const int rowg = lane >> 4;
    const int c    = c0 + col;

    const int rr = r0 + rowg * 4 + HALF;    // pr0 = rr - x
    const int cc = c + HALF;                // pc  = cc - y

    // this block's bin, split into 4-aligned contiguous chunks across the 4 waves
    const int bin = b * NTILES + t;
    const int n   = min(counts[bin], CAP);
    const int qsz = ((n + NW * 4 - 1) / (NW * 4)) * 4;   // per-wave chunk, multiple of 4
    const int lo  = min(n, wid * qsz);
    const int hi  = min(n, lo + qsz);

    const uint4* lst = reinterpret_cast<const uint4*>(entries + (size_t)bin * CAP);

    float a0 = 0.f, a1 = 0.f, a2 = 0.f, a3 = 0.f;
    const float* imgb = img + (size_t)b * E * (P * P);

    uint4 cur = (lo < hi) ? lst[lo >> 2] : make_uint4(0u, 0u, 0u, 0u);
    for (int i = lo; i < hi; i += 4) {
        const uint4 nxt = (i + 4 < hi) ? lst[(i >> 2) + 1] : cur;   // prefetch
        const unsigned pks[4] = {cur.x, cur.y, cur.z, cur.w};
        #pragma unroll
        for (int u = 0; u < 4; ++u) {
            const bool inb = (i + u) < hi;           // wave-uniform
            const unsigned pk = pks[u];
            const int e = (int)(pk & 511u);
            const int x = (int)((pk >> 9) & 255u);
            const int y = (int)(pk >> 17);

            const int pc  = cc - y;                  // patch col (verified math)
            const int pr0 = rr - x;                  // patch row for q=0
            const bool colok = inb && ((unsigned)pc <= 30u);
            const size_t base = (size_t)e * (P * P);
            const bool k0 = colok && ((unsigned)(pr0 + 0) <= 30u);
            const bool k1 = colok && ((unsigned)(pr0 + 1) <= 30u);
            const bool k2 = colok && ((unsigned)(pr0 + 2) <= 30u);
            const bool k3 = colok && ((unsigned)(pr0 + 3) <= 30u);
            a0 += k0 ? imgb[base + (pr0 + 0) * P + pc] : 0.f;
            a1 += k1 ? imgb[base + (pr0 + 1) * P + pc] : 0.f;
            a2 += k2 ? imgb[base + (pr0 + 2) * P + pc] : 0.f;
            a3 += k3 ? imgb[base + (pr0 + 3) * P + pc] : 0.f;
        }
        cur = nxt;
    }

    // ---- reduce the 4 waves' partials in LDS (all accesses lane-consecutive) ----
    __shared__ float part[NW * THREADS];    // 4 KB
    part[wid * THREADS + 0 * 64 + lane] = a0;
    part[wid * THREADS + 1 * 64 + lane] = a1;
    part[wid * THREADS + 2 * 64 + lane] = a2;
    part[wid * THREADS + 3 * 64 + lane] = a3;
    __syncthreads();

    // thread tid owns pixel p=tid: q = tid>>6, lane' = tid&63
    const int q     = tid >> 6;
    const int lane2 = tid & 63;
    const int row   = r0 + ((lane2 >> 4) << 2) + q;
    const int cst   = c0 + (lane2 & 15);
    const float v = part[0 * THREADS + tid] + part[1 * THREADS + tid] +
                    part[2 * THREADS + tid] + part[3 * THREADS + tid];
    if (row < S && cst < S) {
        out[(size_t)b * (S * S) + row * S + cst] = v;
    }
}

extern "C" void kernel_launch(void* const* d_in, const int* in_sizes, int n_in,
                              void* d_out, int out_size, void* d_ws, size_t ws_size,
                              hipStream_t stream)
{
    const float* img = (const float*)d_in[0];   // [B, E, P, P] fp32
    const int*   xyz = (const int*)d_in[1];     // [B, E, 3] int32
    float*       out = (float*)d_out;           // [B, 1, S, S] fp32

    int*      counts  = (int*)d_ws;
    unsigned* entries = (unsigned*)d_ws + NBINS;

    hipMemsetAsync(counts, 0, (size_t)NBINS * sizeof(int), stream);

    imgs4dto3d_bin_kernel<<<B * 2, 256, 0, stream>>>(xyz, counts, entries);

    imgs4dto3d_gather_kernel<<<NBINS, THREADS, 0, stream>>>(img, counts, entries, out);
}

// Round 16
// 49.101 us; speedup vs baseline: 1.7164x; 1.1806x over previous
//
#include <hip/hip_runtime.h>

// Problem constants (match reference)
constexpr int B    = 64;
constexpr int E    = 512;
constexpr int P    = 31;    // patch size
constexpr int S    = 200;   // canvas size
constexpr int HALF = 15;

// Tiling: 16x16 canvas tiles (best test-efficiency: (16+30)^2 window)
constexpr int TS     = 16;
constexpr int NTD    = (S + TS - 1) / TS;    // 13 tiles per dim
constexpr int NTILES = NTD * NTD;            // 169 tiles per batch
constexpr int NBINS  = B * NTILES;           // 10816
constexpr int CAP    = 128;                  // bin capacity (mean ~25, tail ~60)

// Gather launch: one BLOCK per tile; its 4 waves split the bin (R12/R15-verified)
constexpr int THREADS = 256;
constexpr int NW      = THREADS / 64;        // 4 waves
constexpr int NXCD    = 8;

// ---- Binning: one block per batch; counters live in LDS; no global atomics,
// ---- no memset dispatch (counts fully rewritten every call).
__global__ __launch_bounds__(E)
void imgs4dto3d_bin_kernel(const int* __restrict__ xyz,
                           int*       __restrict__ counts,
                           unsigned*  __restrict__ entries)
{
    __shared__ int cnt[NTILES];

    const int b = blockIdx.x;
    const int e = threadIdx.x;                   // one thread per emitter

    for (int i = e; i < NTILES; i += E) cnt[i] = 0;
    __syncthreads();

    const int x = xyz[(size_t)(b * E + e) * 3 + 0];
    const int y = xyz[(size_t)(b * E + e) * 3 + 1];
    const unsigned pk = (unsigned)e | ((unsigned)x << 9) | ((unsigned)y << 17);

    const int tr_lo = (x - HALF) >> 4, tr_hi = (x + HALF) >> 4;
    const int tc_lo = (y - HALF) >> 4, tc_hi = (y + HALF) >> 4;

    for (int tr = tr_lo; tr <= tr_hi; ++tr) {
        for (int tc = tc_lo; tc <= tc_hi; ++tc) {
            const int t   = tr * NTD + tc;
            const int pos = atomicAdd(&cnt[t], 1);          // LDS atomic
            if (pos < CAP)
                entries[(size_t)(b * NTILES + t) * CAP + pos] = pk;
        }
    }
    __syncthreads();

    for (int i = e; i < NTILES; i += E)
        counts[b * NTILES + i] = cnt[i];
}

__global__ __launch_bounds__(THREADS, 8)
void imgs4dto3d_gather_kernel(const float*    __restrict__ img,
                              const int*      __restrict__ counts,
                              const unsigned* __restrict__ entries,
                              float*          __restrict__ out)
{
    // XCD-locality swizzle (R15-verified): all 169 tiles of a batch land on one
    // XCD so the 2 MB batch slab stays L2-resident. gridDim.x = 10816 = 8*1352.
    const int wgid = blockIdx.x;
    const int xcd  = wgid & (NXCD - 1);
    const int seq  = wgid >> 3;
    const int b    = ((seq / NTILES) << 3) | xcd;
    const int t    = seq % NTILES;

    const int tid  = threadIdx.x;
    const int wid  = tid >> 6;
    const int lane = tid & 63;

    const int tr = t / NTD;
    const int tc = t % NTD;
    const int r0 = tr * TS;
    const int c0 = tc * TS;

    // lane map (R6/R12-verified): col = lane&15, rowg = lane>>4; 4 rows per lane
    const int col  = lane & 15;
    const int rowg = lane >> 4;
    const int c    = c0 + col;

    const int rr = r0 + rowg * 4 + HALF;    // pr0 = rr - x
    const int cc = c + HALF;                // pc  = cc - y

    // this block's bin, split into 4-aligned contiguous chunks across the 4 waves
    const int bin = b * NTILES + t;
    const int n   = min(counts[bin], CAP);
    const int qsz = ((n + NW * 4 - 1) / (NW * 4)) * 4;   // per-wave chunk, multiple of 4
    const int lo  = min(n, wid * qsz);
    const int hi  = min(n, lo + qsz);

    const uint4* lst = reinterpret_cast<const uint4*>(entries + (size_t)bin * CAP);

    float a0 = 0.f, a1 = 0.f, a2 = 0.f, a3 = 0.f;
    const float* imgb = img + (size_t)b * E * (P * P);

    uint4 cur = (lo < hi) ? lst[lo >> 2] : make_uint4(0u, 0u, 0u, 0u);
    for (int i = lo; i < hi; i += 4) {
        const uint4 nxt = (i + 4 < hi) ? lst[(i >> 2) + 1] : cur;   // prefetch
        const unsigned pks[4] = {cur.x, cur.y, cur.z, cur.w};
        #pragma unroll
        for (int u = 0; u < 4; ++u) {
            const bool inb = (i + u) < hi;           // wave-uniform
            const unsigned pk = pks[u];
            const int e = (int)(pk & 511u);
            const int x = (int)((pk >> 9) & 255u);
            const int y = (int)(pk >> 17);

            const int pc  = cc - y;                  // patch col (verified math)
            const int pr0 = rr - x;                  // patch row for q=0
            const bool colok = inb && ((unsigned)pc <= 30u);
            const size_t base = (size_t)e * (P * P);
            const bool k0 = colok && ((unsigned)(pr0 + 0) <= 30u);
            const bool k1 = colok && ((unsigned)(pr0 + 1) <= 30u);
            const bool k2 = colok && ((unsigned)(pr0 + 2) <= 30u);
            const bool k3 = colok && ((unsigned)(pr0 + 3) <= 30u);
            a0 += k0 ? imgb[base + (pr0 + 0) * P + pc] : 0.f;
            a1 += k1 ? imgb[base + (pr0 + 1) * P + pc] : 0.f;
            a2 += k2 ? imgb[base + (pr0 + 2) * P + pc] : 0.f;
            a3 += k3 ? imgb[base + (pr0 + 3) * P + pc] : 0.f;
        }
        cur = nxt;
    }

    // ---- reduce the 4 waves' partials in LDS (all accesses lane-consecutive) ----
    __shared__ float part[NW * THREADS];    // 4 KB
    part[wid * THREADS + 0 * 64 + lane] = a0;
    part[wid * THREADS + 1 * 64 + lane] = a1;
    part[wid * THREADS + 2 * 64 + lane] = a2;
    part[wid * THREADS + 3 * 64 + lane] = a3;
    __syncthreads();

    // thread tid owns pixel p=tid: q = tid>>6, lane' = tid&63
    const int q     = tid >> 6;
    const int lane2 = tid & 63;
    const int row   = r0 + ((lane2 >> 4) << 2) + q;
    const int cst   = c0 + (lane2 & 15);
    const float v = part[0 * THREADS + tid] + part[1 * THREADS + tid] +
                    part[2 * THREADS + tid] + part[3 * THREADS + tid];
    if (row < S && cst < S) {
        out[(size_t)b * (S * S) + row * S + cst] = v;
    }
}

extern "C" void kernel_launch(void* const* d_in, const int* in_sizes, int n_in,
                              void* d_out, int out_size, void* d_ws, size_t ws_size,
                              hipStream_t stream)
{
    const float* img = (const float*)d_in[0];   // [B, E, P, P] fp32
    const int*   xyz = (const int*)d_in[1];     // [B, E, 3] int32
    float*       out = (float*)d_out;           // [B, 1, S, S] fp32

    int*      counts  = (int*)d_ws;
    unsigned* entries = (unsigned*)d_ws + NBINS;

    imgs4dto3d_bin_kernel<<<B, E, 0, stream>>>(xyz, counts, entries);

    imgs4dto3d_gather_kernel<<<NBINS, THREADS, 0, stream>>>(img, counts, entries, out);
}

// Round 17
// 36.036 us; speedup vs baseline: 2.3387x; 1.3626x over previous
//
#include <hip/hip_runtime.h>

// Problem constants (match reference)
constexpr int B    = 64;
constexpr int E    = 512;
constexpr int P    = 31;    // patch size
constexpr int S    = 200;   // canvas size
constexpr int HALF = 15;

// Tiling: 16x16 canvas tiles (best test-efficiency: (16+30)^2 window)
constexpr int TS     = 16;
constexpr int NTD    = (S + TS - 1) / TS;    // 13 tiles per dim
constexpr int NTILES = NTD * NTD;            // 169 tiles per batch
constexpr int NBINS  = B * NTILES;           // 10816
constexpr int CAP    = 128;                  // bin capacity (mean ~25, tail ~60)

// Gather launch: one BLOCK per tile; its 4 waves split the bin (R12/R15-verified)
constexpr int THREADS = 256;
constexpr int NW      = THREADS / 64;        // 4 waves
constexpr int NXCD    = 8;

// ---- Binning: one block per batch; counters live in LDS; no global atomics,
// ---- no memset dispatch (counts fully rewritten every call). R16-verified.
__global__ __launch_bounds__(E)
void imgs4dto3d_bin_kernel(const int* __restrict__ xyz,
                           int*       __restrict__ counts,
                           unsigned*  __restrict__ entries)
{
    __shared__ int cnt[NTILES];

    const int b = blockIdx.x;
    const int e = threadIdx.x;                   // one thread per emitter

    for (int i = e; i < NTILES; i += E) cnt[i] = 0;
    __syncthreads();

    const int x = xyz[(size_t)(b * E + e) * 3 + 0];
    const int y = xyz[(size_t)(b * E + e) * 3 + 1];
    const unsigned pk = (unsigned)e | ((unsigned)x << 9) | ((unsigned)y << 17);

    const int tr_lo = (x - HALF) >> 4, tr_hi = (x + HALF) >> 4;
    const int tc_lo = (y - HALF) >> 4, tc_hi = (y + HALF) >> 4;

    for (int tr = tr_lo; tr <= tr_hi; ++tr) {
        for (int tc = tc_lo; tc <= tc_hi; ++tc) {
            const int t   = tr * NTD + tc;
            const int pos = atomicAdd(&cnt[t], 1);          // LDS atomic
            if (pos < CAP)
                entries[(size_t)(b * NTILES + t) * CAP + pos] = pk;
        }
    }
    __syncthreads();

    for (int i = e; i < NTILES; i += E)
        counts[b * NTILES + i] = cnt[i];
}

__global__ __launch_bounds__(THREADS)        // no min-wave cap: give regs to the pipeline
void imgs4dto3d_gather_kernel(const float*    __restrict__ img,
                              const int*      __restrict__ counts,
                              const unsigned* __restrict__ entries,
                              float*          __restrict__ out)
{
    // XCD-locality swizzle (R15-verified): all 169 tiles of a batch land on one
    // XCD so the 2 MB batch slab stays L2-resident. gridDim.x = 10816 = 8*1352.
    const int wgid = blockIdx.x;
    const int xcd  = wgid & (NXCD - 1);
    const int seq  = wgid >> 3;
    const int b    = ((seq / NTILES) << 3) | xcd;
    const int t    = seq % NTILES;

    const int tid  = threadIdx.x;
    const int wid  = tid >> 6;
    const int lane = tid & 63;

    const int tr = t / NTD;
    const int tc = t % NTD;
    const int r0 = tr * TS;
    const int c0 = tc * TS;

    // lane map (R6/R12-verified): col = lane&15, rowg = lane>>4; 4 rows per lane
    const int col  = lane & 15;
    const int rowg = lane >> 4;
    const int c    = c0 + col;

    const int rr = r0 + rowg * 4 + HALF;    // pr0 = rr - x
    const int cc = c + HALF;                // pc  = cc - y

    // this block's bin, split into 4-aligned contiguous chunks across the 4 waves
    const int bin = b * NTILES + t;
    const int n   = min(counts[bin], CAP);
    const int qsz = ((n + NW * 4 - 1) / (NW * 4)) * 4;   // per-wave chunk, multiple of 4
    const int lo  = min(n, wid * qsz);
    const int hi  = min(n, lo + qsz);

    const uint4* lst = reinterpret_cast<const uint4*>(entries + (size_t)bin * CAP);

    float a0 = 0.f, a1 = 0.f, a2 = 0.f, a3 = 0.f;
    const float* imgb = img + (size_t)b * E * (P * P);

    // 8 entries per iteration: decode all, issue all 32 predicated loads into
    // staging registers, then accumulate — one vmcnt round per 8 entries.
    for (int i = lo; i < hi; i += 8) {
        const uint4 ea = lst[i >> 2];                        // i < hi <= n <= CAP
        const uint4 eb = ((i + 4) < hi) ? lst[(i >> 2) + 1] : ea;
        const unsigned pks[8] = {ea.x, ea.y, ea.z, ea.w, eb.x, eb.y, eb.z, eb.w};

        float v[8][4];
        #pragma unroll
        for (int u = 0; u < 8; ++u) {
            const bool inb = (i + u) < hi;                   // wave-uniform
            const unsigned pk = pks[u];
            const int e = (int)(pk & 511u);
            const int x = (int)((pk >> 9) & 255u);
            const int y = (int)(pk >> 17);

            const int pc  = cc - y;                          // patch col (verified math)
            const int pr0 = rr - x;                          // patch row for q=0
            const bool colok = inb && ((unsigned)pc <= 30u);
            const float* bp = imgb + (size_t)e * (P * P) + pr0 * P + pc;
            #pragma unroll
            for (int q = 0; q < 4; ++q) {
                const bool kq = colok && ((unsigned)(pr0 + q) <= 30u);
                v[u][q] = kq ? bp[P * q] : 0.f;              // exec-masked load
            }
        }
        #pragma unroll
        for (int u = 0; u < 8; ++u) {
            a0 += v[u][0]; a1 += v[u][1]; a2 += v[u][2]; a3 += v[u][3];
        }
    }

    // ---- reduce the 4 waves' partials in LDS (all accesses lane-consecutive) ----
    __shared__ float part[NW * THREADS];    // 4 KB
    part[wid * THREADS + 0 * 64 + lane] = a0;
    part[wid * THREADS + 1 * 64 + lane] = a1;
    part[wid * THREADS + 2 * 64 + lane] = a2;
    part[wid * THREADS + 3 * 64 + lane] = a3;
    __syncthreads();

    // thread tid owns pixel p=tid: q = tid>>6, lane' = tid&63
    const int q     = tid >> 6;
    const int lane2 = tid & 63;
    const int row   = r0 + ((lane2 >> 4) << 2) + q;
    const int cst   = c0 + (lane2 & 15);
    const float v = part[0 * THREADS + tid] + part[1 * THREADS + tid] +
                    part[2 * THREADS + tid] + part[3 * THREADS + tid];
    if (row < S && cst < S) {
        out[(size_t)b * (S * S) + row * S + cst] = v;
    }
}

extern "C" void kernel_launch(void* const* d_in, const int* in_sizes, int n_in,
                              void* d_out, int out_size, void* d_ws, size_t ws_size,
                              hipStream_t stream)
{
    const float* img = (const float*)d_in[0];   // [B, E, P, P] fp32
    const int*   xyz = (const int*)d_in[1];     // [B, E, 3] int32
    float*       out = (float*)d_out;           // [B, 1, S, S] fp32

    int*      counts  = (int*)d_ws;
    unsigned* entries = (unsigned*)d_ws + NBINS;

    imgs4dto3d_bin_kernel<<<B, E, 0, stream>>>(xyz, counts, entries);

    imgs4dto3d_gather_kernel<<<NBINS, THREADS, 0, stream>>>(img, counts, entries, out);
}